// Round 8
// baseline (255.806 us; speedup 1.0000x reference)
//
#include <hip/hip_runtime.h>
#include <hip/hip_bf16.h>
#include <stdint.h>

typedef __attribute__((ext_vector_type(8))) short short8;
typedef __attribute__((ext_vector_type(4))) float f32x4;

static __device__ __forceinline__ void gload_lds16(const void* g, void* l) {
  __builtin_amdgcn_global_load_lds((const __attribute__((address_space(1))) void*)g,
                                   (__attribute__((address_space(3))) void*)l,
                                   16, 0, 0);
}

// HW packed f32->bf16 (RNE), 1 inst for 2 values [T12 recipe; gfx950].
static __device__ __forceinline__ unsigned int cvt_pk_bf16(float lo, float hi) {
  unsigned int r;
  asm("v_cvt_pk_bf16_f32 %0, %1, %2" : "=v"(r) : "v"(lo), "v"(hi));
  return r;
}

static __device__ __forceinline__ float max3f(float a, float b, float c) {
  float r;
  asm("v_max3_f32 %0, %1, %2, %3" : "=v"(r) : "v"(a), "v"(b), "v"(c));
  return r;
}

// Counted waits + raw barrier in ONE asm (memory-clobber fences IR motion).
#define WAIT4_BARRIER() asm volatile("s_waitcnt vmcnt(4) lgkmcnt(0)\n\ts_barrier" ::: "memory")
#define WAIT0_BARRIER() asm volatile("s_waitcnt vmcnt(0) lgkmcnt(0)\n\ts_barrier" ::: "memory")

// One fused cast: x (2097152 float4s) then Wq/Wk/Wv/Wo (262144 float4s each).
__global__ void cast_all(const float* __restrict__ x, const float* __restrict__ Wq,
                         const float* __restrict__ Wk, const float* __restrict__ Wv,
                         const float* __restrict__ Wo,
                         unsigned short* __restrict__ xb, unsigned short* __restrict__ Wqb,
                         unsigned short* __restrict__ Wkb, unsigned short* __restrict__ Wvb,
                         unsigned short* __restrict__ Wob) {
  const int i = blockIdx.x * 256 + threadIdx.x;
  const float* src;
  unsigned short* dst;
  int off;
  if (i < 2097152) {
    src = x; dst = xb; off = i;
  } else {
    const int j = i - 2097152;
    const int wsel = j >> 18;
    off = j & 262143;
    src = wsel == 0 ? Wq : wsel == 1 ? Wk : wsel == 2 ? Wv : Wo;
    dst = wsel == 0 ? Wqb : wsel == 1 ? Wkb : wsel == 2 ? Wvb : Wob;
  }
  float4 v = reinterpret_cast<const float4*>(src)[off];
  uint2 o;
  o.x = cvt_pk_bf16(v.x, v.y);
  o.y = cvt_pk_bf16(v.z, v.w);
  reinterpret_cast<uint2*>(dst)[off] = o;
}

// 128x128-tile GEMM body, K=1024, NT (A[M,1024] x B[N,1024]^T).
// Triple-buffered LDS (lookahead-2 staging), counted vmcnt(4) + raw barrier,
// conflict-free XOR swizzle for 64B rows: s(row) = ((row>>1)&3)<<4.
template <typename OutT>
static __device__ __forceinline__ void gemm_tile(const unsigned short* __restrict__ A,
                                                 const unsigned short* __restrict__ B,
                                                 OutT* __restrict__ C,
                                                 int brow, int bcol, int ldc,
                                                 short* sA, short* sB, float oscale) {
  const int t = threadIdx.x;
  const int w = t >> 6, l = t & 63, lg = l >> 4, lr = l & 15;
  const int wr = w >> 1, wc = w & 1;

  f32x4 acc[4][4] = {};

  auto stage = [&](int buf, int kt) {
#pragma unroll
    for (int r = 0; r < 2; ++r) {
      const int byteoff = t * 16 + r * 4096;      // 8 KB per matrix-tile
      const int row = byteoff >> 6;               // 64 B per row (32 bf16)
      const int inrow = (byteoff & 63) ^ (((row >> 1) & 3) << 4);  // inv-swz src
      gload_lds16((const char*)A + ((size_t)(brow + row) * 1024 + kt) * 2 + inrow,
                  (char*)(sA + buf * 4096) + byteoff);
      gload_lds16((const char*)B + ((size_t)(bcol + row) * 1024 + kt) * 2 + inrow,
                  (char*)(sB + buf * 4096) + byteoff);
    }
  };

  stage(0, 0);
  stage(1, 32);
  int cur = 0;

  for (int kti = 0; kti < 32; ++kti) {
    if (kti < 31) WAIT4_BARRIER();  // tile kti landed; tile kti+1 stays in flight
    else         WAIT0_BARRIER();
    if (kti + 2 < 32) {
      int b2 = cur + 2; if (b2 >= 3) b2 -= 3;
      stage(b2, (kti + 2) << 5);
    }
    const char* sAc = (const char*)(sA + cur * 4096);
    const char* sBc = (const char*)(sB + cur * 4096);

    short8 af[4], bfr[4];
#pragma unroll
    for (int m = 0; m < 4; ++m) {
      const int arow = wr * 64 + m * 16 + lr;
      af[m] = *reinterpret_cast<const short8*>(
          sAc + arow * 64 + ((lg * 16) ^ (((arow >> 1) & 3) << 4)));
    }
#pragma unroll
    for (int n = 0; n < 4; ++n) {
      const int brw = wc * 64 + n * 16 + lr;
      bfr[n] = *reinterpret_cast<const short8*>(
          sBc + brw * 64 + ((lg * 16) ^ (((brw >> 1) & 3) << 4)));
    }
    __builtin_amdgcn_s_setprio(1);
#pragma unroll
    for (int m = 0; m < 4; ++m)
#pragma unroll
      for (int n = 0; n < 4; ++n)
        acc[m][n] = __builtin_amdgcn_mfma_f32_16x16x32_bf16(af[m], bfr[n], acc[m][n], 0, 0, 0);
    __builtin_amdgcn_s_setprio(0);

    ++cur; if (cur == 3) cur = 0;
  }

  // C/D layout: col = lane&15, row = (lane>>4)*4 + reg  [m89 verified]
#pragma unroll
  for (int m = 0; m < 4; ++m) {
#pragma unroll
    for (int n = 0; n < 4; ++n) {
      const size_t i0 = (size_t)(brow + wr * 64 + m * 16 + lg * 4) * ldc +
                        (bcol + wc * 64 + n * 16 + lr);
      if constexpr (sizeof(OutT) == 2) {
        // pack j-pairs with HW cvt_pk (replaces 4 scalar RNE sequences)
        const unsigned int v01 = cvt_pk_bf16(acc[m][n][0] * oscale, acc[m][n][1] * oscale);
        const unsigned int v23 = cvt_pk_bf16(acc[m][n][2] * oscale, acc[m][n][3] * oscale);
        C[i0]            = (OutT)(v01 & 0xffffu);
        C[i0 + ldc]      = (OutT)(v01 >> 16);
        C[i0 + 2 * ldc]  = (OutT)(v23 & 0xffffu);
        C[i0 + 3 * ldc]  = (OutT)(v23 >> 16);
      } else {
#pragma unroll
        for (int j = 0; j < 4; ++j) C[i0 + (size_t)j * ldc] = acc[m][n][j] * oscale;
      }
    }
  }
}

// Fused Q/K/V projections: 1536 blocks, XCD-chunked.
// Q output pre-scaled by 1/sqrt(dk)*log2(e) (QK^T lands in exp2 domain).
__global__ __launch_bounds__(256) void gemm_qkv(const unsigned short* __restrict__ xb,
                                                const unsigned short* __restrict__ Wqb,
                                                const unsigned short* __restrict__ Wkb,
                                                const unsigned short* __restrict__ Wvb,
                                                unsigned short* __restrict__ Qb,
                                                unsigned short* __restrict__ Kb,
                                                unsigned short* __restrict__ Vt) {
  __shared__ short sA[3][4096];
  __shared__ short sB[3][4096];
  const int i = blockIdx.x;
  const int lid = (i & 7) * 192 + (i >> 3);  // bijective: 1536 = 8*192
  const int z = lid >> 9, r = lid & 511;

  const unsigned short *A, *B;
  unsigned short* C;
  int brow, bcol, ldc;
  float oscale = 1.0f;
  if (z == 2) {
    A = Wvb; B = xb; C = Vt;
    brow = (r & 7) << 7; bcol = (r >> 3) << 7; ldc = 8192;
  } else {
    A = xb; B = z ? Wkb : Wqb; C = z ? Kb : Qb;
    brow = (r >> 3) << 7; bcol = (r & 7) << 7; ldc = 1024;
    if (z == 0) oscale = 0.125f * 1.44269504089f;  // 1/sqrt(dk) * log2(e)
  }
  gemm_tile<unsigned short>(A, B, C, brow, bcol, ldc, sA[0], sB[0], oscale);
}

// Final projection: out = AO Wo^T, f32 out. 512 blocks, XCD-chunked.
__global__ __launch_bounds__(256) void gemm_out(const unsigned short* __restrict__ AO,
                                                const unsigned short* __restrict__ Wob,
                                                float* __restrict__ out) {
  __shared__ short sA[3][4096];
  __shared__ short sB[3][4096];
  const int i = blockIdx.x;
  const int lid = (i & 7) * 64 + (i >> 3);  // bijective: 512 = 8*64
  gemm_tile<float>(AO, Wob, out, (lid >> 3) << 7, (lid & 7) << 7, 1024,
                   sA[0], sB[0], 1.0f);
}

// Causal flash attention: swapped-QK^T per-lane softmax, paired q-tiles
// flattened into one 33-tile sequence, double-buffered K/V (4 blocks/CU),
// Q pre-scaled (exp2 domain), defer-max, setprio, HW cvt_pk P-pack,
// max3 reduce, lane-partial lsum (cross-lane reduce deferred to epilogue).
__global__ __launch_bounds__(256) void attn_kernel(const unsigned short* __restrict__ Qg,
                                                   const unsigned short* __restrict__ Kg,
                                                   const unsigned short* __restrict__ Vtg,
                                                   unsigned short* __restrict__ AO) {
  const int S = 2048, D = 1024, SN = 8192;
  const int i = blockIdx.x;
  const int lid = (i & 7) * 128 + (i >> 3);  // XCD k <- lids [128k,128k+128)
  const int qp = lid & 15;
  const int bh = lid >> 4;
  const int b = bh >> 4, h = bh & 15;
  const int t = threadIdx.x;
  const int w = t >> 6, l = t & 63, lg = l >> 4, lr = l & 15;

  __shared__ short sK[2][4096];  // [kv=64][dk=64], XOR-swizzled 128B rows
  __shared__ short sV[2][4096];  // [dk=64][kv=64] (=V^T), XOR-swizzled
  __shared__ short sP[4096];     // per-wave P[q=16][kv=64], XOR-swizzled

  int sboff[2], slin[2], srow[2];
#pragma unroll
  for (int r = 0; r < 2; ++r) {
    sboff[r] = t * 16 + r * 4096;
    srow[r] = sboff[r] >> 7;                            // 128 B per row
    slin[r] = (sboff[r] & 127) ^ ((srow[r] & 7) << 4);  // inverse-swizzled src
  }
  const char* Kbase = (const char*)Kg + ((size_t)(b * S) * D + h * 64) * 2;
  const char* Vbase = (const char*)Vtg + ((size_t)(h * 64) * SN + (size_t)b * S) * 2;

  const int nkv0 = qp + 1;       // half0: qt=qp, tiles 0..qp
  const int qt1 = 31 - qp;       // half1: qt=31-qp, tiles 0..31-qp (33 total)

  auto stage = [&](int buf, int j) {
    const int kvt = (j < nkv0) ? j : j - nkv0;
    const size_t kv0 = (size_t)kvt * 64;
#pragma unroll
    for (int r = 0; r < 2; ++r) {
      gload_lds16(Kbase + (kv0 + srow[r]) * 2048 + slin[r],
                  (char*)sK + buf * 8192 + sboff[r]);
      gload_lds16(Vbase + (size_t)srow[r] * 16384 + kv0 * 2 + slin[r],
                  (char*)sV + buf * 8192 + sboff[r]);
    }
  };
  auto load_qf = [&](int qt, short8* qf) {
    const unsigned short* qbase =
        Qg + (size_t)(b * S + qt * 64 + w * 16 + lr) * D + h * 64;
    qf[0] = *reinterpret_cast<const short8*>(qbase + lg * 8);
    qf[1] = *reinterpret_cast<const short8*>(qbase + 32 + lg * 8);
  };

  short8 qf[2], qfB[2];
  load_qf(qp, qf);       // both halves' Q preloaded at prologue
  load_qf(qt1, qfB);
  stage(0, 0);

  f32x4 o[4] = {};
  float m = -INFINITY, ls = 0.f;  // ls = per-lane partial of lsum
  int cur = 0;

  auto epilogue = [&](int qt) {
    float lsum = ls;
    lsum += __shfl_xor(lsum, 16);
    lsum += __shfl_xor(lsum, 32);
    const float inv = 1.f / lsum;
    unsigned short* orow = AO + (size_t)(b * S + qt * 64 + w * 16 + lr) * D + h * 64;
#pragma unroll
    for (int dn = 0; dn < 4; ++dn) {
      uint2 ov;
      ov.x = cvt_pk_bf16(o[dn][0] * inv, o[dn][1] * inv);
      ov.y = cvt_pk_bf16(o[dn][2] * inv, o[dn][3] * inv);
      *reinterpret_cast<uint2*>(orow + dn * 16 + lg * 4) = ov;
    }
  };

  WAIT0_BARRIER();  // tile 0 staged

#pragma unroll 1
  for (int j = 0; j < 33; ++j) {
    const bool h1 = (j >= nkv0);
    const int kvt = h1 ? j - nkv0 : j;
    const int qt = h1 ? qt1 : qp;

    if (j + 1 < 33) stage(cur ^ 1, j + 1);  // latency hidden by this iter

    const char* sKc = (const char*)sK + cur * 8192;
    const char* sVc = (const char*)sV + cur * 8192;

    // S^T (exp2-domain, Q pre-scaled): sc[n][r] at lane (lg,lr) =
    //   S[q = w*16+lr][kv = n*16 + lg*4 + r]
    f32x4 sc[4] = {};
    __builtin_amdgcn_s_setprio(1);
#pragma unroll
    for (int n = 0; n < 4; ++n) {
#pragma unroll
      for (int kk = 0; kk < 2; ++kk) {
        const int row = n * 16 + lr;
        const short8 kf = *reinterpret_cast<const short8*>(
            sKc + (row << 7) + ((kk * 64 + lg * 16) ^ ((row & 7) << 4)));
        sc[n] = __builtin_amdgcn_mfma_f32_16x16x32_bf16(kf, qf[kk], sc[n], 0, 0, 0);
      }
    }
    __builtin_amdgcn_s_setprio(0);

    // causal mask (diagonal tile only); no scale mul needed (pre-scaled Q)
    if (kvt == qt) {
      const int ql = w * 16 + lr;
#pragma unroll
      for (int n = 0; n < 4; ++n)
#pragma unroll
        for (int r = 0; r < 4; ++r)
          if ((n * 16 + lg * 4 + r) > ql) sc[n][r] = -INFINITY;
    }

    // per-lane online softmax with defer-max (T13, THR=8 in log2 domain);
    // max tree via v_max3 (7 ops for 16 values)
    float t0 = max3f(sc[0][0], sc[0][1], sc[0][2]);
    float t1 = max3f(sc[0][3], sc[1][0], sc[1][1]);
    float t2 = max3f(sc[1][2], sc[1][3], sc[2][0]);
    float t3 = max3f(sc[2][1], sc[2][2], sc[2][3]);
    float t4 = max3f(sc[3][0], sc[3][1], sc[3][2]);
    float mx = fmaxf(max3f(t0, t1, t2), max3f(t3, t4, sc[3][3]));
    mx = fmaxf(mx, __shfl_xor(mx, 16));
    mx = fmaxf(mx, __shfl_xor(mx, 32));
    if (!__all(mx <= m + 8.0f)) {
      const float mnew = fmaxf(m, mx);
      const float alpha = __builtin_amdgcn_exp2f(m - mnew);  // row-uniform
      m = mnew;
      ls *= alpha;
#pragma unroll
      for (int dn = 0; dn < 4; ++dn) o[dn] *= alpha;
    }

    float p[4][4];
    float s = 0.f;
#pragma unroll
    for (int n = 0; n < 4; ++n) {
#pragma unroll
      for (int r = 0; r < 4; ++r) {
        const float e = __builtin_amdgcn_exp2f(sc[n][r] - m);
        p[n][r] = e;
        s += e;
      }
    }
    ls += s;  // cross-lane reduce deferred to epilogue

    // P -> sP (rows = q = lr), wave-private; HW cvt_pk pack (8B write)
#pragma unroll
    for (int n = 0; n < 4; ++n) {
      uint2 pk;
      pk.x = cvt_pk_bf16(p[n][0], p[n][1]);
      pk.y = cvt_pk_bf16(p[n][2], p[n][3]);
      *reinterpret_cast<uint2*>(
          (char*)sP + (w << 11) + (lr << 7) + ((n * 32 + lg * 8) ^ ((lr & 7) << 4))) = pk;
    }

    // O^T += Vt . P^T
    __builtin_amdgcn_s_setprio(1);
#pragma unroll
    for (int kk = 0; kk < 2; ++kk) {
      const short8 pa = *reinterpret_cast<const short8*>(
          (const char*)sP + (w << 11) + (lr << 7) +
          ((kk * 64 + lg * 16) ^ ((lr & 7) << 4)));
#pragma unroll
      for (int dn = 0; dn < 4; ++dn) {
        const int vrow = dn * 16 + lr;
        const short8 vb = *reinterpret_cast<const short8*>(
            sVc + (vrow << 7) + ((kk * 64 + lg * 16) ^ ((vrow & 7) << 4)));
        o[dn] = __builtin_amdgcn_mfma_f32_16x16x32_bf16(vb, pa, o[dn], 0, 0, 0);
      }
    }
    __builtin_amdgcn_s_setprio(0);

    if (j == nkv0 - 1) {  // end of half0: store, reset, switch Q
      epilogue(qp);
#pragma unroll
      for (int dn = 0; dn < 4; ++dn) o[dn] = f32x4{0.f, 0.f, 0.f, 0.f};
      m = -INFINITY; ls = 0.f;
      qf[0] = qfB[0]; qf[1] = qfB[1];
    }

    if (j + 1 < 33) WAIT0_BARRIER();  // next tile staged; guards buf reuse
    cur ^= 1;
  }
  epilogue(qt1);
}

extern "C" void kernel_launch(void* const* d_in, const int* in_sizes, int n_in,
                              void* d_out, int out_size, void* d_ws, size_t ws_size,
                              hipStream_t stream) {
  const float* x  = (const float*)d_in[0];
  const float* Wq = (const float*)d_in[1];
  const float* Wk = (const float*)d_in[2];
  const float* Wv = (const float*)d_in[3];
  const float* Wo = (const float*)d_in[4];
  float* out = (float*)d_out;

  char* ws = (char*)d_ws;
  unsigned short* xb  = (unsigned short*)(ws);               // 8192x1024 (16 MB)
  unsigned short* Wqb = (unsigned short*)(ws + 16777216);
  unsigned short* Wkb = (unsigned short*)(ws + 18874368);
  unsigned short* Wvb = (unsigned short*)(ws + 20971520);
  unsigned short* Wob = (unsigned short*)(ws + 23068672);
  unsigned short* Qb  = (unsigned short*)(ws + 25165824);    // 8192x1024
  unsigned short* Kb  = (unsigned short*)(ws + 41943040);    // 8192x1024
  unsigned short* Vt  = (unsigned short*)(ws + 58720256);    // 1024x8192 (V^T)
  unsigned short* AO  = (unsigned short*)(ws + 75497472);    // 8192x1024

  cast_all<<<12288, 256, 0, stream>>>(x, Wq, Wk, Wv, Wo, xb, Wqb, Wkb, Wvb, Wob);
  gemm_qkv<<<1536, 256, 0, stream>>>(xb, Wqb, Wkb, Wvb, Qb, Kb, Vt);
  attn_kernel<<<1024, 256, 0, stream>>>(Qb, Kb, Vt, AO);
  gemm_out<<<512, 256, 0, stream>>>(AO, Wob, out);
}